// Round 3
// baseline (845.572 us; speedup 1.0000x reference)
//
#include <hip/hip_runtime.h>
#include <stdint.h>

// Connected-components post-processor, MI355X (gfx950).
// B=8, C=4, H=W=768. 24 masks (b, class 1..3), 4-connected CCL, keep largest
// component (tie -> smallest min-raster-seed label), bg = 1 - sum(fg).
//
// Pipeline (4 kernels, no memset):
//   k_init          argmax -> parent (pix | -1); zero count scratch; zero best;
//                   then intra-slab (768x4 rows) union-find in the same kernel
//   k_bridge        union of the cross-slab vertical edges only (191 rows)
//   k_flatten_count path-compress + wave-run-length size atomics
//                   + packed (partial_size, ~root) block atomicMax -> best
//   k_final         fg = (parent == best_root), bg = 1 - sum(fg)

constexpr int BB    = 8;
constexpr int CC    = 4;
constexpr int HH    = 768;
constexpr int WW    = 768;
constexpr int HWP   = HH * WW;          // 589824
constexpr int NMASK = BB * (CC - 1);    // 24
constexpr int TPB   = 256;
constexpr int NBLK  = HWP / TPB;        // 2304 (no tail)
constexpr int NBLK4 = HWP / (4 * TPB);  // 576

constexpr int SLAB_ROWS = 4;
constexpr int NSLAB     = HH / SLAB_ROWS;          // 192
constexpr int GR_SLAB   = SLAB_ROWS * (WW / 4);    // 768 float4-groups per slab
constexpr int NBOUND    = (NSLAB - 1) * WW;        // 146688 cross-slab edges/mask
constexpr int NBLK_BR   = (NBOUND + TPB - 1) / TPB;// 573

__device__ __forceinline__ int findroot(const int* __restrict__ P, int x) {
  int p = P[x];
  while (p != x) { x = p; p = P[x]; }   // historic values are <= x: terminates
  return x;
}

// Link-to-min union-find with retry. Parent values only decrease; atomicMin's
// return value is coherent ground truth, so stale plain loads only cost extra
// iterations (max(a,b) strictly decreases per failed attempt -> terminates).
__device__ __forceinline__ void unite(int* P, int a, int b) {
  a = findroot(P, a);
  b = findroot(P, b);
  while (a != b) {
    if (a < b) { int t = a; a = b; b = t; }   // a > b: link a under b
    int old = atomicMin(&P[a], b);
    if (old == a) return;                     // linked root a -> b
    a = findroot(P, old);
    b = findroot(P, b);
  }
}

// 1) argmax -> parent init; zero count scratch (fg channels of d_out); zero
//    best[]; then union all edges interior to this block's 768x4-row slab.
//    Every parent entry touched in phase 2 was written by this same block.
__global__ void __launch_bounds__(TPB)
k_init(const float* __restrict__ pred, int* __restrict__ parent,
       float* __restrict__ out, unsigned long long* __restrict__ best) {
  int s = blockIdx.x;                       // slab (rows [4s, 4s+4))
  int b = blockIdx.y;
  int t = threadIdx.x;
  const float4* base = (const float4*)(pred + (size_t)b * CC * HWP);
  float4 z4 = make_float4(0.f, 0.f, 0.f, 0.f);

#pragma unroll
  for (int i = 0; i < 3; ++i) {             // 768 groups, 256 threads
    int g = s * GR_SLAB + i * TPB + t;      // float4-group index
    float4 v0 = base[g];
    float4 v1 = base[(size_t)(HWP / 4) + g];
    float4 v2 = base[(size_t)(HWP / 4) * 2 + g];
    float4 v3 = base[(size_t)(HWP / 4) * 3 + g];
    float c0[4] = {v0.x, v0.y, v0.z, v0.w};
    float c1[4] = {v1.x, v1.y, v1.z, v1.w};
    float c2[4] = {v2.x, v2.y, v2.z, v2.w};
    float c3[4] = {v3.x, v3.y, v3.z, v3.w};
    int pix0 = g * 4;
    int pa[3][4];
#pragma unroll
    for (int j = 0; j < 4; ++j) {
      float bv = c0[j]; int am = 0;         // strict > keeps FIRST max (jnp.argmax)
      if (c1[j] > bv) { bv = c1[j]; am = 1; }
      if (c2[j] > bv) { bv = c2[j]; am = 2; }
      if (c3[j] > bv) { bv = c3[j]; am = 3; }
      pa[0][j] = (am == 1) ? pix0 + j : -1;
      pa[1][j] = (am == 2) ? pix0 + j : -1;
      pa[2][j] = (am == 3) ? pix0 + j : -1;
    }
#pragma unroll
    for (int cm = 0; cm < 3; ++cm) {
      ((int4*)(parent + (size_t)(b * 3 + cm) * HWP))[g] =
          make_int4(pa[cm][0], pa[cm][1], pa[cm][2], pa[cm][3]);
      ((float4*)(out + (size_t)(b * CC + 1 + cm) * HWP))[g] = z4;  // counts = 0
    }
  }
  if (s == 0 && b == 0 && t < NMASK) best[t] = 0ull;

  __syncthreads();   // block's parent writes drained before any parent read

  // Phase 2: union edges fully inside the slab (right edges + down edges from
  // slab-rows 0..2).  Down edges from slab-row 3 are handled by k_bridge.
#pragma unroll
  for (int cm = 0; cm < 3; ++cm) {
    int* P = parent + (size_t)(b * 3 + cm) * HWP;
#pragma unroll
    for (int i = 0; i < 3; ++i) {
      int p0 = (s * GR_SLAB + i * TPB + t) * 4;
#pragma unroll
      for (int j = 0; j < 4; ++j) {
        int p = p0 + j;
        if (P[p] < 0) continue;
        int x    = p - (p / WW) * WW;
        int rins = (p / WW) & (SLAB_ROWS - 1);
        if (x + 1 < WW && P[p + 1] >= 0) unite(P, p, p + 1);
        if (rins < SLAB_ROWS - 1 && P[p + WW] >= 0) unite(P, p, p + WW);
      }
    }
  }
}

// 2) cross-slab vertical edges: rows (4k+3, 4k+4), k = 0..190.
__global__ void __launch_bounds__(TPB)
k_bridge(int* __restrict__ parent) {
  int bp = blockIdx.x * TPB + threadIdx.x;
  if (bp >= NBOUND) return;
  int* P = parent + (size_t)blockIdx.y * HWP;
  int k = bp / WW;
  int x = bp - k * WW;
  int p = (SLAB_ROWS * k + SLAB_ROWS - 1) * WW + x;
  if (P[p] >= 0 && P[p + WW] >= 0) unite(P, p, p + WW);
}

// 3) flatten + count + best, fused.
//    Wave-aggregated size atomics (one per run of equal roots); atomicAdd's
//    return value gives a running partial sum -> pack(partial, ~root),
//    block-max, one atomicMax per block.  Global max over all partials equals
//    max over component totals (each root's LAST add returns its total), and
//    ~root in the low word breaks size ties toward the smallest root.
__global__ void __launch_bounds__(TPB)
k_flatten_count(int* __restrict__ parent, uint32_t* __restrict__ out_u32,
                unsigned long long* __restrict__ best) {
  int pix = blockIdx.x * TPB + threadIdx.x;
  int m   = blockIdx.y;
  int* P  = parent + (size_t)m * HWP;
  int pv  = P[pix];
  int r   = -1;
  if (pv >= 0) {
    r = (pv == pix) ? pix : findroot(P, pv);
    if (r != pv) P[pix] = r;
  }
  int lane = threadIdx.x & 63;
  int prev = __shfl_up(r, 1);
  bool bound = (lane == 0) || (prev != r);
  unsigned long long lb = __ballot(bound);
  unsigned long long pack = 0ull;
  if (bound && r >= 0) {
    unsigned long long rest = (lane == 63) ? 0ull : (lb >> (lane + 1));
    int nxt = rest ? (lane + 1 + (int)__builtin_ctzll(rest)) : 64;
    int len = nxt - lane;
    int b = m / 3, cm = m - b * 3;
    uint32_t* cnt = out_u32 + (size_t)(b * CC + 1 + cm) * HWP;
    uint32_t old = atomicAdd(cnt + r, (uint32_t)len);
    pack = (((unsigned long long)(old + (uint32_t)len)) << 32) |
           (unsigned long long)(0xFFFFFFFFu - (uint32_t)r);
  }
#pragma unroll
  for (int off = 32; off > 0; off >>= 1) {
    unsigned long long o = __shfl_down(pack, off);
    if (o > pack) pack = o;
  }
  __shared__ unsigned long long sm[TPB / 64];
  int wid = threadIdx.x >> 6;
  if (lane == 0) sm[wid] = pack;
  __syncthreads();
  if (threadIdx.x == 0) {
    unsigned long long bm = sm[0];
#pragma unroll
    for (int i = 1; i < TPB / 64; ++i) if (sm[i] > bm) bm = sm[i];
    if (bm) atomicMax(best + m, bm);
  }
}

// 4) write all 4 output channels (4 pixels/thread).
__global__ void __launch_bounds__(TPB)
k_final(const int* __restrict__ parent, const unsigned long long* __restrict__ best,
        float* __restrict__ out) {
  int g = blockIdx.x * TPB + threadIdx.x;
  int b = blockIdx.y;
  float s[4] = {0.f, 0.f, 0.f, 0.f};
  float4 f[3];
#pragma unroll
  for (int cm = 0; cm < 3; ++cm) {
    unsigned long long bv = best[b * 3 + cm];            // uniform -> scalar load
    int root = (bv >> 32) ? (int)(0xFFFFFFFFu - (uint32_t)bv) : -2;  // -2: empty
    int4 pv = ((const int4*)(parent + (size_t)(b * 3 + cm) * HWP))[g];
    float4 fv = make_float4(pv.x == root ? 1.f : 0.f, pv.y == root ? 1.f : 0.f,
                            pv.z == root ? 1.f : 0.f, pv.w == root ? 1.f : 0.f);
    f[cm] = fv;
    s[0] += fv.x; s[1] += fv.y; s[2] += fv.z; s[3] += fv.w;
  }
  float4* ob = (float4*)(out + (size_t)b * CC * HWP);
  ob[g] = make_float4(s[0] > 0.f ? 0.f : 1.f, s[1] > 0.f ? 0.f : 1.f,
                      s[2] > 0.f ? 0.f : 1.f, s[3] > 0.f ? 0.f : 1.f);
  ob[(size_t)(HWP / 4)     + g] = f[0];
  ob[(size_t)(HWP / 4) * 2 + g] = f[1];
  ob[(size_t)(HWP / 4) * 3 + g] = f[2];
}

extern "C" void kernel_launch(void* const* d_in, const int* in_sizes, int n_in,
                              void* d_out, int out_size, void* d_ws, size_t ws_size,
                              hipStream_t stream) {
  const float* pred = (const float*)d_in[0];
  float* out = (float*)d_out;

  int* parent = (int*)d_ws;   // 24 * 589824 * 4 B = 56.6 MB
  unsigned long long* best =
      (unsigned long long*)((char*)d_ws + (size_t)NMASK * HWP * sizeof(int));

  dim3 blk(TPB);
  k_init          <<<dim3(NSLAB, BB),     blk, 0, stream>>>(pred, parent, out, best);
  k_bridge        <<<dim3(NBLK_BR, NMASK), blk, 0, stream>>>(parent);
  k_flatten_count <<<dim3(NBLK, NMASK),   blk, 0, stream>>>(parent, (uint32_t*)out, best);
  k_final         <<<dim3(NBLK4, BB),     blk, 0, stream>>>(parent, best, out);
}

// Round 5
// 397.807 us; speedup vs baseline: 2.1256x; 2.1256x over previous
//
#include <hip/hip_runtime.h>
#include <stdint.h>

// Connected-components post-processor, MI355X (gfx950).
// B=8, C=4, H=W=768. 24 masks (b, class 1..3), 4-connected CCL, keep largest
// component (tie -> smallest min-raster-seed label), bg = 1 - sum(fg).
//
// Pipeline (5 kernels, no memset):
//   k_init          argmax -> parent (pix | -1); zero count scratch;
//                   then intra-slab (768x4 rows) union-find in the same kernel
//   k_bridge        union of the cross-slab vertical edges only (191 rows)
//   k_flatten_count path-compress + wave-run-length size atomics; per-block
//                   packed (partial_size, ~root) max -> PLAIN store to scratch
//                   (R3 profile: per-block atomicMax into 24 hot words = 536us
//                   of cross-XCD line ping-pong, VALUBusy 5.9% -> replaced)
//   k_reduce_best   24 blocks: max-reduce 2304 block maxima -> best[m]
//   k_final         fg = (parent == best_root), bg = 1 - sum(fg)

constexpr int BB    = 8;
constexpr int CC    = 4;
constexpr int HH    = 768;
constexpr int WW    = 768;
constexpr int HWP   = HH * WW;          // 589824
constexpr int NMASK = BB * (CC - 1);    // 24
constexpr int TPB   = 256;
constexpr int NBLK  = HWP / TPB;        // 2304 (no tail)
constexpr int NBLK4 = HWP / (4 * TPB);  // 576

constexpr int SLAB_ROWS = 4;
constexpr int NSLAB     = HH / SLAB_ROWS;          // 192
constexpr int GR_SLAB   = SLAB_ROWS * (WW / 4);    // 768 float4-groups per slab
constexpr int NBOUND    = (NSLAB - 1) * WW;        // 146688 cross-slab edges/mask
constexpr int NBLK_BR   = (NBOUND + TPB - 1) / TPB;// 573

__device__ __forceinline__ int findroot(const int* __restrict__ P, int x) {
  int p = P[x];
  while (p != x) { x = p; p = P[x]; }   // historic values are <= x: terminates
  return x;
}

// Link-to-min union-find with retry. Parent values only decrease; atomicMin's
// return value is coherent ground truth, so stale plain loads only cost extra
// iterations (max(a,b) strictly decreases per failed attempt -> terminates).
__device__ __forceinline__ void unite(int* P, int a, int b) {
  a = findroot(P, a);
  b = findroot(P, b);
  while (a != b) {
    if (a < b) { int t = a; a = b; b = t; }   // a > b: link a under b
    int old = atomicMin(&P[a], b);
    if (old == a) return;                     // linked root a -> b
    a = findroot(P, old);
    b = findroot(P, b);
  }
}

// 1) argmax -> parent init; zero count scratch (fg channels of d_out);
//    then union all edges interior to this block's 768x4-row slab.
//    Every parent entry touched in phase 2 was written by this same block
//    (roots stay slab-local until k_bridge), so no cross-block hazards.
__global__ void __launch_bounds__(TPB)
k_init(const float* __restrict__ pred, int* __restrict__ parent,
       float* __restrict__ out) {
  int s = blockIdx.x;                       // slab (rows [4s, 4s+4))
  int b = blockIdx.y;
  int t = threadIdx.x;
  const float4* base = (const float4*)(pred + (size_t)b * CC * HWP);
  float4 z4 = make_float4(0.f, 0.f, 0.f, 0.f);

#pragma unroll
  for (int i = 0; i < 3; ++i) {             // 768 groups, 256 threads
    int g = s * GR_SLAB + i * TPB + t;      // float4-group index
    float4 v0 = base[g];
    float4 v1 = base[(size_t)(HWP / 4) + g];
    float4 v2 = base[(size_t)(HWP / 4) * 2 + g];
    float4 v3 = base[(size_t)(HWP / 4) * 3 + g];
    float c0[4] = {v0.x, v0.y, v0.z, v0.w};
    float c1[4] = {v1.x, v1.y, v1.z, v1.w};
    float c2[4] = {v2.x, v2.y, v2.z, v2.w};
    float c3[4] = {v3.x, v3.y, v3.z, v3.w};
    int pix0 = g * 4;
    int pa[3][4];
#pragma unroll
    for (int j = 0; j < 4; ++j) {
      float bv = c0[j]; int am = 0;         // strict > keeps FIRST max (jnp.argmax)
      if (c1[j] > bv) { bv = c1[j]; am = 1; }
      if (c2[j] > bv) { bv = c2[j]; am = 2; }
      if (c3[j] > bv) { bv = c3[j]; am = 3; }
      pa[0][j] = (am == 1) ? pix0 + j : -1;
      pa[1][j] = (am == 2) ? pix0 + j : -1;
      pa[2][j] = (am == 3) ? pix0 + j : -1;
    }
#pragma unroll
    for (int cm = 0; cm < 3; ++cm) {
      ((int4*)(parent + (size_t)(b * 3 + cm) * HWP))[g] =
          make_int4(pa[cm][0], pa[cm][1], pa[cm][2], pa[cm][3]);
      ((float4*)(out + (size_t)(b * CC + 1 + cm) * HWP))[g] = z4;  // counts = 0
    }
  }

  __syncthreads();   // block's parent writes drained before any parent read

  // Phase 2: union edges fully inside the slab (right edges + down edges from
  // slab-rows 0..2).  Down edges from slab-row 3 are handled by k_bridge.
#pragma unroll
  for (int cm = 0; cm < 3; ++cm) {
    int* P = parent + (size_t)(b * 3 + cm) * HWP;
#pragma unroll
    for (int i = 0; i < 3; ++i) {
      int p0 = (s * GR_SLAB + i * TPB + t) * 4;
#pragma unroll
      for (int j = 0; j < 4; ++j) {
        int p = p0 + j;
        if (P[p] < 0) continue;
        int x    = p - (p / WW) * WW;
        int rins = (p / WW) & (SLAB_ROWS - 1);
        if (x + 1 < WW && P[p + 1] >= 0) unite(P, p, p + 1);
        if (rins < SLAB_ROWS - 1 && P[p + WW] >= 0) unite(P, p, p + WW);
      }
    }
  }
}

// 2) cross-slab vertical edges: rows (4k+3, 4k+4), k = 0..190.
__global__ void __launch_bounds__(TPB)
k_bridge(int* __restrict__ parent) {
  int bp = blockIdx.x * TPB + threadIdx.x;
  if (bp >= NBOUND) return;
  int* P = parent + (size_t)blockIdx.y * HWP;
  int k = bp / WW;
  int x = bp - k * WW;
  int p = (SLAB_ROWS * k + SLAB_ROWS - 1) * WW + x;
  if (P[p] >= 0 && P[p + WW] >= 0) unite(P, p, p + WW);
}

// 3) flatten + count, fused.  Wave-aggregated size atomics (one per run of
//    equal roots); atomicAdd's return gives a running partial -> pack
//    (partial, ~root); block max PLAIN-stored to blockmax[m][bx].
//    Max over all partials == max over totals (each root's LAST add returns
//    its total); ~root low word breaks ties toward smallest root.
__global__ void __launch_bounds__(TPB)
k_flatten_count(int* __restrict__ parent, uint32_t* __restrict__ out_u32,
                unsigned long long* __restrict__ blockmax) {
  int pix = blockIdx.x * TPB + threadIdx.x;
  int m   = blockIdx.y;
  int* P  = parent + (size_t)m * HWP;
  int pv  = P[pix];
  int r   = -1;
  if (pv >= 0) {
    r = (pv == pix) ? pix : findroot(P, pv);
    if (r != pv) P[pix] = r;
  }
  int lane = threadIdx.x & 63;
  int prev = __shfl_up(r, 1);
  bool bound = (lane == 0) || (prev != r);
  unsigned long long lb = __ballot(bound);
  unsigned long long pack = 0ull;
  if (bound && r >= 0) {
    unsigned long long rest = (lane == 63) ? 0ull : (lb >> (lane + 1));
    int nxt = rest ? (lane + 1 + (int)__builtin_ctzll(rest)) : 64;
    int len = nxt - lane;
    int b = m / 3, cm = m - b * 3;
    uint32_t* cnt = out_u32 + (size_t)(b * CC + 1 + cm) * HWP;
    uint32_t old = atomicAdd(cnt + r, (uint32_t)len);
    pack = (((unsigned long long)(old + (uint32_t)len)) << 32) |
           (unsigned long long)(0xFFFFFFFFu - (uint32_t)r);
  }
#pragma unroll
  for (int off = 32; off > 0; off >>= 1) {
    unsigned long long o = __shfl_down(pack, off);
    if (o > pack) pack = o;
  }
  __shared__ unsigned long long sm[TPB / 64];
  int wid = threadIdx.x >> 6;
  if (lane == 0) sm[wid] = pack;
  __syncthreads();
  if (threadIdx.x == 0) {
    unsigned long long bm = sm[0];
#pragma unroll
    for (int i = 1; i < TPB / 64; ++i) if (sm[i] > bm) bm = sm[i];
    blockmax[(size_t)m * NBLK + blockIdx.x] = bm;   // plain store, no contention
  }
}

// 4) reduce 2304 block maxima per mask -> best[m].  24 blocks.
__global__ void __launch_bounds__(TPB)
k_reduce_best(const unsigned long long* __restrict__ blockmax,
              unsigned long long* __restrict__ best) {
  int m = blockIdx.x;
  const unsigned long long* bm = blockmax + (size_t)m * NBLK;
  unsigned long long v = 0ull;
  for (int i = threadIdx.x; i < NBLK; i += TPB) {
    unsigned long long o = bm[i];
    if (o > v) v = o;
  }
#pragma unroll
  for (int off = 32; off > 0; off >>= 1) {
    unsigned long long o = __shfl_down(v, off);
    if (o > v) v = o;
  }
  __shared__ unsigned long long sm[TPB / 64];
  int lane = threadIdx.x & 63, wid = threadIdx.x >> 6;
  if (lane == 0) sm[wid] = v;
  __syncthreads();
  if (threadIdx.x == 0) {
    unsigned long long b0 = sm[0];
#pragma unroll
    for (int i = 1; i < TPB / 64; ++i) if (sm[i] > b0) b0 = sm[i];
    best[m] = b0;                       // 0 when mask empty
  }
}

// 5) write all 4 output channels (4 pixels/thread).
__global__ void __launch_bounds__(TPB)
k_final(const int* __restrict__ parent, const unsigned long long* __restrict__ best,
        float* __restrict__ out) {
  int g = blockIdx.x * TPB + threadIdx.x;
  int b = blockIdx.y;
  float s[4] = {0.f, 0.f, 0.f, 0.f};
  float4 f[3];
#pragma unroll
  for (int cm = 0; cm < 3; ++cm) {
    unsigned long long bv = best[b * 3 + cm];            // uniform -> scalar load
    int root = (bv >> 32) ? (int)(0xFFFFFFFFu - (uint32_t)bv) : -2;  // -2: empty
    int4 pv = ((const int4*)(parent + (size_t)(b * 3 + cm) * HWP))[g];
    float4 fv = make_float4(pv.x == root ? 1.f : 0.f, pv.y == root ? 1.f : 0.f,
                            pv.z == root ? 1.f : 0.f, pv.w == root ? 1.f : 0.f);
    f[cm] = fv;
    s[0] += fv.x; s[1] += fv.y; s[2] += fv.z; s[3] += fv.w;
  }
  float4* ob = (float4*)(out + (size_t)b * CC * HWP);
  ob[g] = make_float4(s[0] > 0.f ? 0.f : 1.f, s[1] > 0.f ? 0.f : 1.f,
                      s[2] > 0.f ? 0.f : 1.f, s[3] > 0.f ? 0.f : 1.f);
  ob[(size_t)(HWP / 4)     + g] = f[0];
  ob[(size_t)(HWP / 4) * 2 + g] = f[1];
  ob[(size_t)(HWP / 4) * 3 + g] = f[2];
}

extern "C" void kernel_launch(void* const* d_in, const int* in_sizes, int n_in,
                              void* d_out, int out_size, void* d_ws, size_t ws_size,
                              hipStream_t stream) {
  const float* pred = (const float*)d_in[0];
  float* out = (float*)d_out;

  int* parent = (int*)d_ws;   // 24 * 589824 * 4 B = 56.6 MB
  unsigned long long* best =
      (unsigned long long*)((char*)d_ws + (size_t)NMASK * HWP * sizeof(int));
  // Block-max scratch lives in the batch-0 bg-channel region of d_out
  // (out[0 .. HWP)):  24*2304*8 B = 442 KB < 2.36 MB.  Disjoint from the
  // count scratch (fg channels), fully overwritten later by k_final.
  unsigned long long* blockmax = (unsigned long long*)out;

  dim3 blk(TPB);
  k_init          <<<dim3(NSLAB, BB),      blk, 0, stream>>>(pred, parent, out);
  k_bridge        <<<dim3(NBLK_BR, NMASK), blk, 0, stream>>>(parent);
  k_flatten_count <<<dim3(NBLK, NMASK),    blk, 0, stream>>>(parent, (uint32_t*)out, blockmax);
  k_reduce_best   <<<dim3(NMASK),          blk, 0, stream>>>(blockmax, best);
  k_final         <<<dim3(NBLK4, BB),      blk, 0, stream>>>(parent, best, out);
}

// Round 7
// 276.829 us; speedup vs baseline: 3.0545x; 1.4370x over previous
//
#include <hip/hip_runtime.h>
#include <stdint.h>

// Connected-components post-processor, MI355X (gfx950).
// B=8, C=4, H=W=768. 24 masks (b, class 1..3), 4-connected CCL, keep largest
// component (tie -> smallest min-raster-seed label), bg = 1 - sum(fg).
//
// Pipeline (5 kernels, no memset):
//   k_init          argmax -> class codes; per-mask intra-slab CCL in LDS
//                   (R5 profile: global-atomic intra-slab unions = 184us,
//                    FETCH 137MB vs 75.5MB ideal, VALUBusy 10% -> LDS unions,
//                    parent written once, never re-read here)
//   k_bridge        union of the cross-slab vertical edges only (191 rows)
//   k_flatten_count path-compress + wave-run-length size atomics; per-block
//                   packed (partial_size, ~root) max -> PLAIN store to scratch
//                   (R3: atomicMax into 24 hot words = 536us ping-pong -> this)
//   k_reduce_best   24 blocks: max-reduce 2304 block maxima -> best[m]
//   k_final         fg = (parent == best_root), bg = 1 - sum(fg)

constexpr int BB    = 8;
constexpr int CC    = 4;
constexpr int HH    = 768;
constexpr int WW    = 768;
constexpr int HWP   = HH * WW;          // 589824
constexpr int NMASK = BB * (CC - 1);    // 24
constexpr int TPB   = 256;
constexpr int NBLK  = HWP / TPB;        // 2304 (no tail)
constexpr int NBLK4 = HWP / (4 * TPB);  // 576

constexpr int SLAB_ROWS = 4;
constexpr int SLAB_PIX  = SLAB_ROWS * WW;          // 3072 pixels per slab
constexpr int NSLAB     = HH / SLAB_ROWS;          // 192
constexpr int GR_SLAB   = SLAB_PIX / 4;            // 768 float4-groups per slab
constexpr int NBOUND    = (NSLAB - 1) * WW;        // 146688 cross-slab edges/mask
constexpr int NBLK_BR   = (NBOUND + TPB - 1) / TPB;// 573

__device__ __forceinline__ int findroot(const int* __restrict__ P, int x) {
  int p = P[x];
  while (p != x) { x = p; p = P[x]; }   // historic values are <= x: terminates
  return x;
}

// Global link-to-min union-find with retry (used by k_bridge only now).
__device__ __forceinline__ void unite(int* P, int a, int b) {
  a = findroot(P, a);
  b = findroot(P, b);
  while (a != b) {
    if (a < b) { int t = a; a = b; b = t; }   // a > b: link a under b
    int old = atomicMin(&P[a], b);
    if (old == a) return;                     // linked root a -> b
    a = findroot(P, old);
    b = findroot(P, b);
  }
}

// 1) argmax -> class codes; zero count scratch; per-mask slab CCL in LDS;
//    parent written once (slab-rooted labels), never re-read in this kernel.
//    Correctness: bg lp stays -1 (unions never touch it); fg lp values only
//    decrease and stay >= 0; barriers separate init/union/flatten phases.
__global__ void __launch_bounds__(TPB)
k_init(const float* __restrict__ pred, int* __restrict__ parent,
       float* __restrict__ out) {
  __shared__ int lp[SLAB_PIX];              // 12 KB local union-find
  int s = blockIdx.x;                       // slab (rows [4s, 4s+4))
  int b = blockIdx.y;
  int t = threadIdx.x;
  const float4* base = (const float4*)(pred + (size_t)b * CC * HWP);
  float4 z4 = make_float4(0.f, 0.f, 0.f, 0.f);

  unsigned char am[3][4];                   // argmax class per handled pixel
#pragma unroll
  for (int i = 0; i < 3; ++i) {             // 768 groups, 256 threads
    int g = s * GR_SLAB + i * TPB + t;      // float4-group index
    float4 v0 = base[g];
    float4 v1 = base[(size_t)(HWP / 4) + g];
    float4 v2 = base[(size_t)(HWP / 4) * 2 + g];
    float4 v3 = base[(size_t)(HWP / 4) * 3 + g];
    float c0[4] = {v0.x, v0.y, v0.z, v0.w};
    float c1[4] = {v1.x, v1.y, v1.z, v1.w};
    float c2[4] = {v2.x, v2.y, v2.z, v2.w};
    float c3[4] = {v3.x, v3.y, v3.z, v3.w};
#pragma unroll
    for (int j = 0; j < 4; ++j) {
      float bv = c0[j]; int a = 0;          // strict > keeps FIRST max (jnp.argmax)
      if (c1[j] > bv) { bv = c1[j]; a = 1; }
      if (c2[j] > bv) { bv = c2[j]; a = 2; }
      if (c3[j] > bv) { bv = c3[j]; a = 3; }
      am[i][j] = (unsigned char)a;
    }
#pragma unroll
    for (int cm = 0; cm < 3; ++cm)
      ((float4*)(out + (size_t)(b * CC + 1 + cm) * HWP))[g] = z4;  // counts = 0
  }

  // LDS union-find helpers (lambdas keep addrspace(3) visible to compiler).
  auto lfind = [&](int x) {
    int p = lp[x];
    while (p != x) { x = p; p = lp[x]; }
    return x;
  };
  auto lunite = [&](int a, int c) {
    a = lfind(a); c = lfind(c);
    while (a != c) {
      if (a < c) { int tmp = a; a = c; c = tmp; }
      int old = atomicMin(&lp[a], c);
      if (old == a) return;
      a = lfind(old); c = lfind(c);
    }
  };

#pragma unroll
  for (int cm = 0; cm < 3; ++cm) {
    __syncthreads();                        // lp free (prev mask done reading)
    // init lp: local pixel index if this mask's fg, else -1
#pragma unroll
    for (int i = 0; i < 3; ++i) {
      int l0 = (i * TPB + t) * 4;
      int4 iv;
      iv.x = (am[i][0] == cm + 1) ? l0     : -1;
      iv.y = (am[i][1] == cm + 1) ? l0 + 1 : -1;
      iv.z = (am[i][2] == cm + 1) ? l0 + 2 : -1;
      iv.w = (am[i][3] == cm + 1) ? l0 + 3 : -1;
      *(int4*)&lp[l0] = iv;
    }
    __syncthreads();
    // union right + down edges inside the slab (LDS atomics)
#pragma unroll
    for (int i = 0; i < 3; ++i) {
      int l0  = (i * TPB + t) * 4;
      int row = l0 / WW;                    // 0..3 (4-groups never straddle rows)
      int col0 = l0 - row * WW;
#pragma unroll
      for (int j = 0; j < 4; ++j) {
        int l = l0 + j;
        if (lp[l] < 0) continue;
        if (col0 + j + 1 < WW && lp[l + 1] >= 0)  lunite(l, l + 1);
        if (row < SLAB_ROWS - 1 && lp[l + WW] >= 0) lunite(l, l + WW);
      }
    }
    __syncthreads();
    // flatten + write global parent (slab-rooted labels), coalesced int4
    int gbase = s * SLAB_PIX;
    int* Pch = parent + (size_t)(b * 3 + cm) * HWP;
#pragma unroll
    for (int i = 0; i < 3; ++i) {
      int l0 = (i * TPB + t) * 4;
      int4 pv;
      pv.x = (lp[l0]     >= 0) ? gbase + lfind(l0)     : -1;
      pv.y = (lp[l0 + 1] >= 0) ? gbase + lfind(l0 + 1) : -1;
      pv.z = (lp[l0 + 2] >= 0) ? gbase + lfind(l0 + 2) : -1;
      pv.w = (lp[l0 + 3] >= 0) ? gbase + lfind(l0 + 3) : -1;
      ((int4*)Pch)[s * GR_SLAB + i * TPB + t] = pv;
    }
  }
}

// 2) cross-slab vertical edges: rows (4k+3, 4k+4), k = 0..190.
__global__ void __launch_bounds__(TPB)
k_bridge(int* __restrict__ parent) {
  int bp = blockIdx.x * TPB + threadIdx.x;
  if (bp >= NBOUND) return;
  int* P = parent + (size_t)blockIdx.y * HWP;
  int k = bp / WW;
  int x = bp - k * WW;
  int p = (SLAB_ROWS * k + SLAB_ROWS - 1) * WW + x;
  if (P[p] >= 0 && P[p + WW] >= 0) unite(P, p, p + WW);
}

// 3) flatten + count, fused.  Wave-aggregated size atomics (one per run of
//    equal roots); atomicAdd's return gives a running partial -> pack
//    (partial, ~root); block max PLAIN-stored to blockmax[m][bx].
//    Max over all partials == max over totals (each root's LAST add returns
//    its total); ~root low word breaks ties toward smallest root.
__global__ void __launch_bounds__(TPB)
k_flatten_count(int* __restrict__ parent, uint32_t* __restrict__ out_u32,
                unsigned long long* __restrict__ blockmax) {
  int pix = blockIdx.x * TPB + threadIdx.x;
  int m   = blockIdx.y;
  int* P  = parent + (size_t)m * HWP;
  int pv  = P[pix];
  int r   = -1;
  if (pv >= 0) {
    r = (pv == pix) ? pix : findroot(P, pv);
    if (r != pv) P[pix] = r;
  }
  int lane = threadIdx.x & 63;
  int prev = __shfl_up(r, 1);
  bool bound = (lane == 0) || (prev != r);
  unsigned long long lb = __ballot(bound);
  unsigned long long pack = 0ull;
  if (bound && r >= 0) {
    unsigned long long rest = (lane == 63) ? 0ull : (lb >> (lane + 1));
    int nxt = rest ? (lane + 1 + (int)__builtin_ctzll(rest)) : 64;
    int len = nxt - lane;
    int b = m / 3, cm = m - b * 3;
    uint32_t* cnt = out_u32 + (size_t)(b * CC + 1 + cm) * HWP;
    uint32_t old = atomicAdd(cnt + r, (uint32_t)len);
    pack = (((unsigned long long)(old + (uint32_t)len)) << 32) |
           (unsigned long long)(0xFFFFFFFFu - (uint32_t)r);
  }
#pragma unroll
  for (int off = 32; off > 0; off >>= 1) {
    unsigned long long o = __shfl_down(pack, off);
    if (o > pack) pack = o;
  }
  __shared__ unsigned long long sm[TPB / 64];
  int wid = threadIdx.x >> 6;
  if (lane == 0) sm[wid] = pack;
  __syncthreads();
  if (threadIdx.x == 0) {
    unsigned long long bm = sm[0];
#pragma unroll
    for (int i = 1; i < TPB / 64; ++i) if (sm[i] > bm) bm = sm[i];
    blockmax[(size_t)m * NBLK + blockIdx.x] = bm;   // plain store, no contention
  }
}

// 4) reduce 2304 block maxima per mask -> best[m].  24 blocks.
__global__ void __launch_bounds__(TPB)
k_reduce_best(const unsigned long long* __restrict__ blockmax,
              unsigned long long* __restrict__ best) {
  int m = blockIdx.x;
  const unsigned long long* bm = blockmax + (size_t)m * NBLK;
  unsigned long long v = 0ull;
  for (int i = threadIdx.x; i < NBLK; i += TPB) {
    unsigned long long o = bm[i];
    if (o > v) v = o;
  }
#pragma unroll
  for (int off = 32; off > 0; off >>= 1) {
    unsigned long long o = __shfl_down(v, off);
    if (o > v) v = o;
  }
  __shared__ unsigned long long sm[TPB / 64];
  int lane = threadIdx.x & 63, wid = threadIdx.x >> 6;
  if (lane == 0) sm[wid] = v;
  __syncthreads();
  if (threadIdx.x == 0) {
    unsigned long long b0 = sm[0];
#pragma unroll
    for (int i = 1; i < TPB / 64; ++i) if (sm[i] > b0) b0 = sm[i];
    best[m] = b0;                       // 0 when mask empty
  }
}

// 5) write all 4 output channels (4 pixels/thread).
__global__ void __launch_bounds__(TPB)
k_final(const int* __restrict__ parent, const unsigned long long* __restrict__ best,
        float* __restrict__ out) {
  int g = blockIdx.x * TPB + threadIdx.x;
  int b = blockIdx.y;
  float s[4] = {0.f, 0.f, 0.f, 0.f};
  float4 f[3];
#pragma unroll
  for (int cm = 0; cm < 3; ++cm) {
    unsigned long long bv = best[b * 3 + cm];            // uniform -> scalar load
    int root = (bv >> 32) ? (int)(0xFFFFFFFFu - (uint32_t)bv) : -2;  // -2: empty
    int4 pv = ((const int4*)(parent + (size_t)(b * 3 + cm) * HWP))[g];
    float4 fv = make_float4(pv.x == root ? 1.f : 0.f, pv.y == root ? 1.f : 0.f,
                            pv.z == root ? 1.f : 0.f, pv.w == root ? 1.f : 0.f);
    f[cm] = fv;
    s[0] += fv.x; s[1] += fv.y; s[2] += fv.z; s[3] += fv.w;
  }
  float4* ob = (float4*)(out + (size_t)b * CC * HWP);
  ob[g] = make_float4(s[0] > 0.f ? 0.f : 1.f, s[1] > 0.f ? 0.f : 1.f,
                      s[2] > 0.f ? 0.f : 1.f, s[3] > 0.f ? 0.f : 1.f);
  ob[(size_t)(HWP / 4)     + g] = f[0];
  ob[(size_t)(HWP / 4) * 2 + g] = f[1];
  ob[(size_t)(HWP / 4) * 3 + g] = f[2];
}

extern "C" void kernel_launch(void* const* d_in, const int* in_sizes, int n_in,
                              void* d_out, int out_size, void* d_ws, size_t ws_size,
                              hipStream_t stream) {
  const float* pred = (const float*)d_in[0];
  float* out = (float*)d_out;

  int* parent = (int*)d_ws;   // 24 * 589824 * 4 B = 56.6 MB
  unsigned long long* best =
      (unsigned long long*)((char*)d_ws + (size_t)NMASK * HWP * sizeof(int));
  // Block-max scratch lives in the batch-0 bg-channel region of d_out
  // (out[0 .. HWP)):  24*2304*8 B = 442 KB < 2.36 MB.  Disjoint from the
  // count scratch (fg channels), fully overwritten later by k_final.
  unsigned long long* blockmax = (unsigned long long*)out;

  dim3 blk(TPB);
  k_init          <<<dim3(NSLAB, BB),      blk, 0, stream>>>(pred, parent, out);
  k_bridge        <<<dim3(NBLK_BR, NMASK), blk, 0, stream>>>(parent);
  k_flatten_count <<<dim3(NBLK, NMASK),    blk, 0, stream>>>(parent, (uint32_t*)out, blockmax);
  k_reduce_best   <<<dim3(NMASK),          blk, 0, stream>>>(blockmax, best);
  k_final         <<<dim3(NBLK4, BB),      blk, 0, stream>>>(parent, best, out);
}

// Round 8
// 224.139 us; speedup vs baseline: 3.7725x; 1.2351x over previous
//
#include <hip/hip_runtime.h>
#include <stdint.h>

// Connected-components post-processor, MI355X (gfx950).
// B=8, C=4, H=W=768. argmax over channels -> 3 disjoint class masks per batch,
// 4-connected CCL per mask, keep largest component (tie -> smallest min-raster
// seed), bg = 1 - sum(fg).
//
// R7 restructure: masks are DISJOINT -> single packed parent per batch:
//   parent[b][pix] = (class << 20) | label   (class 1..3; bg = -1)
// Unions only link same-class pixels => class bits constant along chains;
// atomicMin on packed == atomicMin on label. Cuts parent/count state 3x
// (R7 profile: k_init WRITE 110.6MB, 4.7M LDS conflicts; k_flatten FETCH
//  65.7MB - all scale with the 3-channel representation).
//
// Pipeline:
//   k_init          argmax -> packed class codes; ONE intra-slab LDS CCL pass;
//                   parent written once; zero per-batch count scratch
//   k_bridge        cross-slab vertical edges, same-class only (grid x B)
//   k_flatten_count path-compress + wave-run-length count atomics; per-class
//                   packed (partial,~root) block max -> plain store (R3: hot
//                   atomicMax = 536us ping-pong -> blockmax + k_reduce_best)
//   k_reduce_best   24 blocks: max-reduce 2304 block maxima -> best[m]
//   k_final         fg = (packed parent == (cls,best_root)), bg = !match

constexpr int BB    = 8;
constexpr int CC    = 4;
constexpr int HH    = 768;
constexpr int WW    = 768;
constexpr int HWP   = HH * WW;          // 589824 < 2^20
constexpr int NMASK = BB * (CC - 1);    // 24
constexpr int TPB   = 256;
constexpr int NBLK  = HWP / TPB;        // 2304 (no tail)
constexpr int NBLK4 = HWP / (4 * TPB);  // 576

constexpr int SLAB_ROWS = 4;
constexpr int SLAB_PIX  = SLAB_ROWS * WW;          // 3072
constexpr int NSLAB     = HH / SLAB_ROWS;          // 192
constexpr int GR_SLAB   = SLAB_PIX / 4;            // 768 int4-groups per slab
constexpr int NBOUND    = (NSLAB - 1) * WW;        // 146688 edges per batch
constexpr int NBLK_BR   = (NBOUND + TPB - 1) / TPB;// 573 (exact)

constexpr int CSH  = 20;                 // global packed: class<<20 | pix
constexpr int LMSK = (1 << CSH) - 1;
constexpr int LSH  = 12;                 // local packed: class<<12 | lpix (<3072)
constexpr int LLMSK = (1 << LSH) - 1;

__device__ __forceinline__ int findroot(const int* __restrict__ P, int x) {
  int l = P[x] & LMSK;
  while (l != x) { x = l; l = P[x] & LMSK; }   // labels only decrease: terminates
  return x;
}

// Same-class link-to-min union-find with retry (global, packed values).
__device__ __forceinline__ void unite(int* P, int a, int b, int cls) {
  a = findroot(P, a);
  b = findroot(P, b);
  while (a != b) {
    if (a < b) { int t = a; a = b; b = t; }     // a > b: link a under b
    int old = atomicMin(&P[a], (cls << CSH) | b);
    if ((old & LMSK) == a) return;              // a was root: linked
    a = findroot(P, old & LMSK);
    b = findroot(P, b);
  }
}

// 1) argmax -> packed classes; zero count scratch (channel 1 of this batch in
//    d_out); single LDS CCL pass over all 3 classes (disjoint); parent written
//    once with slab-rooted packed labels, never re-read here.
__global__ void __launch_bounds__(TPB)
k_init(const float* __restrict__ pred, int* __restrict__ parent,
       float* __restrict__ out) {
  __shared__ int lp[SLAB_PIX];              // 12 KB packed local union-find
  int s = blockIdx.x;                       // slab (rows [4s, 4s+4))
  int b = blockIdx.y;
  int t = threadIdx.x;
  const float4* base = (const float4*)(pred + (size_t)b * CC * HWP);
  int4* cntz = (int4*)(out + (size_t)(b * CC + 1) * HWP);   // count scratch
  int4 z4 = make_int4(0, 0, 0, 0);

  unsigned char am[3][4];                   // argmax class (0..3) per pixel
#pragma unroll
  for (int i = 0; i < 3; ++i) {             // 768 groups, 256 threads
    int g = s * GR_SLAB + i * TPB + t;
    float4 v0 = base[g];
    float4 v1 = base[(size_t)(HWP / 4) + g];
    float4 v2 = base[(size_t)(HWP / 4) * 2 + g];
    float4 v3 = base[(size_t)(HWP / 4) * 3 + g];
    float c0[4] = {v0.x, v0.y, v0.z, v0.w};
    float c1[4] = {v1.x, v1.y, v1.z, v1.w};
    float c2[4] = {v2.x, v2.y, v2.z, v2.w};
    float c3[4] = {v3.x, v3.y, v3.z, v3.w};
#pragma unroll
    for (int j = 0; j < 4; ++j) {
      float bv = c0[j]; int a = 0;          // strict > keeps FIRST max (jnp.argmax)
      if (c1[j] > bv) { bv = c1[j]; a = 1; }
      if (c2[j] > bv) { bv = c2[j]; a = 2; }
      if (c3[j] > bv) { bv = c3[j]; a = 3; }
      am[i][j] = (unsigned char)a;
    }
    cntz[g] = z4;                           // zero counts for this batch
    int l0 = (i * TPB + t) * 4;
    int4 iv;
    iv.x = am[i][0] ? ((int)am[i][0] << LSH) | l0       : -1;
    iv.y = am[i][1] ? ((int)am[i][1] << LSH) | (l0 + 1) : -1;
    iv.z = am[i][2] ? ((int)am[i][2] << LSH) | (l0 + 2) : -1;
    iv.w = am[i][3] ? ((int)am[i][3] << LSH) | (l0 + 3) : -1;
    *(int4*)&lp[l0] = iv;
  }

  auto lfind = [&](int x) {
    int l = lp[x] & LLMSK;
    while (l != x) { x = l; l = lp[x] & LLMSK; }
    return x;
  };
  auto lunite = [&](int a, int c, int cls) {
    a = lfind(a); c = lfind(c);
    while (a != c) {
      if (a < c) { int tmp = a; a = c; c = tmp; }
      int old = atomicMin(&lp[a], (cls << LSH) | c);
      if ((old & LLMSK) == a) return;
      a = lfind(old & LLMSK);
      c = lfind(c);
    }
  };

  __syncthreads();
  // union right + down edges inside the slab, same class only (one pass!)
#pragma unroll
  for (int i = 0; i < 3; ++i) {
    int l0   = (i * TPB + t) * 4;
    int row  = l0 / WW;                     // 0..3 (groups never straddle rows)
    int col0 = l0 - row * WW;
#pragma unroll
    for (int j = 0; j < 4; ++j) {
      int l = l0 + j;
      int cls = am[i][j];
      if (!cls) continue;
      if (col0 + j + 1 < WW) {
        int nv = lp[l + 1];
        if (nv >= 0 && (nv >> LSH) == cls) lunite(l, l + 1, cls);
      }
      if (row < SLAB_ROWS - 1) {
        int nv = lp[l + WW];
        if (nv >= 0 && (nv >> LSH) == cls) lunite(l, l + WW, cls);
      }
    }
  }
  __syncthreads();
  // flatten + write packed global parent (slab-rooted), coalesced int4
  int gbase = s * SLAB_PIX;
  int* Pb = parent + (size_t)b * HWP;
#pragma unroll
  for (int i = 0; i < 3; ++i) {
    int l0 = (i * TPB + t) * 4;
    int4 pv;
    pv.x = (lp[l0]     >= 0) ? ((lp[l0]     >> LSH) << CSH) | (gbase + lfind(l0))     : -1;
    pv.y = (lp[l0 + 1] >= 0) ? ((lp[l0 + 1] >> LSH) << CSH) | (gbase + lfind(l0 + 1)) : -1;
    pv.z = (lp[l0 + 2] >= 0) ? ((lp[l0 + 2] >> LSH) << CSH) | (gbase + lfind(l0 + 2)) : -1;
    pv.w = (lp[l0 + 3] >= 0) ? ((lp[l0 + 3] >> LSH) << CSH) | (gbase + lfind(l0 + 3)) : -1;
    ((int4*)Pb)[s * GR_SLAB + i * TPB + t] = pv;
  }
}

// 2) cross-slab vertical edges: rows (4k+3, 4k+4), same class only.
__global__ void __launch_bounds__(TPB)
k_bridge(int* __restrict__ parent) {
  int bp = blockIdx.x * TPB + threadIdx.x;
  if (bp >= NBOUND) return;
  int* P = parent + (size_t)blockIdx.y * HWP;
  int k = bp / WW;
  int x = bp - k * WW;
  int p = (SLAB_ROWS * k + SLAB_ROWS - 1) * WW + x;
  int pv = P[p], qv = P[p + WW];
  if (pv >= 0 && qv >= 0 && ((pv ^ qv) >> CSH) == 0)
    unite(P, p, p + WW, pv >> CSH);
}

// 3) flatten + count, fused.  Wave-aggregated size atomics (one per run of
//    equal roots; equal root => equal class); atomicAdd's return gives the
//    running partial -> pack(partial, ~root); per-class block max plain-stored
//    to blockmax[b*3+cm][bx].  Max over partials == max over totals.
__global__ void __launch_bounds__(TPB)
k_flatten_count(int* __restrict__ parent, float* __restrict__ out,
                unsigned long long* __restrict__ blockmax) {
  int pix = blockIdx.x * TPB + threadIdx.x;
  int b   = blockIdx.y;
  int* P  = parent + (size_t)b * HWP;
  int pv  = P[pix];
  int r = -1, cls = 0;
  if (pv >= 0) {
    cls = pv >> CSH;
    int lbl = pv & LMSK;
    r = (lbl == pix) ? pix : findroot(P, lbl);
    if (r != lbl) P[pix] = (cls << CSH) | r;
  }
  int lane = threadIdx.x & 63;
  int prev = __shfl_up(r, 1);
  bool bound = (lane == 0) || (prev != r);
  unsigned long long lb = __ballot(bound);
  unsigned long long pack = 0ull;
  if (bound && r >= 0) {
    unsigned long long rest = (lane == 63) ? 0ull : (lb >> (lane + 1));
    int nxt = rest ? (lane + 1 + (int)__builtin_ctzll(rest)) : 64;
    int len = nxt - lane;
    uint32_t* cnt = (uint32_t*)(out + (size_t)(b * CC + 1) * HWP);
    uint32_t old = atomicAdd(cnt + r, (uint32_t)len);
    pack = (((unsigned long long)(old + (uint32_t)len)) << 32) |
           (unsigned long long)(0xFFFFFFFFu - (uint32_t)r);
  }
  __shared__ unsigned long long sm[3][TPB / 64];
  int wid = threadIdx.x >> 6;
#pragma unroll
  for (int cm = 0; cm < 3; ++cm) {
    unsigned long long pc = (cls == cm + 1) ? pack : 0ull;
#pragma unroll
    for (int off = 32; off > 0; off >>= 1) {
      unsigned long long o = __shfl_down(pc, off);
      if (o > pc) pc = o;
    }
    if (lane == 0) sm[cm][wid] = pc;
  }
  __syncthreads();
  if (threadIdx.x < 3) {
    int cm = threadIdx.x;
    unsigned long long bm = sm[cm][0];
#pragma unroll
    for (int i = 1; i < TPB / 64; ++i) if (sm[cm][i] > bm) bm = sm[cm][i];
    blockmax[(size_t)(b * 3 + cm) * NBLK + blockIdx.x] = bm;  // plain store
  }
}

// 4) reduce 2304 block maxima per (batch,class) -> best[m].  24 blocks.
__global__ void __launch_bounds__(TPB)
k_reduce_best(const unsigned long long* __restrict__ blockmax,
              unsigned long long* __restrict__ best) {
  int m = blockIdx.x;
  const unsigned long long* bm = blockmax + (size_t)m * NBLK;
  unsigned long long v = 0ull;
  for (int i = threadIdx.x; i < NBLK; i += TPB) {
    unsigned long long o = bm[i];
    if (o > v) v = o;
  }
#pragma unroll
  for (int off = 32; off > 0; off >>= 1) {
    unsigned long long o = __shfl_down(v, off);
    if (o > v) v = o;
  }
  __shared__ unsigned long long sm[TPB / 64];
  int lane = threadIdx.x & 63, wid = threadIdx.x >> 6;
  if (lane == 0) sm[wid] = v;
  __syncthreads();
  if (threadIdx.x == 0) {
    unsigned long long b0 = sm[0];
#pragma unroll
    for (int i = 1; i < TPB / 64; ++i) if (sm[i] > b0) b0 = sm[i];
    best[m] = b0;                       // 0 when mask empty
  }
}

// 5) write all 4 output channels (4 pixels/thread, one packed parent read).
__global__ void __launch_bounds__(TPB)
k_final(const int* __restrict__ parent, const unsigned long long* __restrict__ best,
        float* __restrict__ out) {
  int g = blockIdx.x * TPB + threadIdx.x;
  int b = blockIdx.y;
  int broot[3];
#pragma unroll
  for (int cm = 0; cm < 3; ++cm) {
    unsigned long long bv = best[b * 3 + cm];            // uniform -> scalar
    broot[cm] = (bv >> 32) ? (int)(0xFFFFFFFFu - (uint32_t)bv) : -2;  // -2: empty
  }
  int4 pv = ((const int4*)(parent + (size_t)b * HWP))[g];
  int pvs[4] = {pv.x, pv.y, pv.z, pv.w};
  float4 ch[4];
  float* chf = (float*)ch;
#pragma unroll
  for (int c = 0; c < 4; ++c) ch[c] = make_float4(0.f, 0.f, 0.f, 0.f);
#pragma unroll
  for (int j = 0; j < 4; ++j) {
    int v = pvs[j];
    if (v >= 0) {
      int cls = v >> CSH;                  // 1..3
      bool match = (v & LMSK) == broot[cls - 1];
      chf[cls * 4 + j] = match ? 1.f : 0.f;
      chf[j]           = match ? 0.f : 1.f;   // bg
    } else {
      chf[j] = 1.f;                        // bg pixel
    }
  }
  float4* ob = (float4*)(out + (size_t)b * CC * HWP);
#pragma unroll
  for (int c = 0; c < 4; ++c)
    ob[(size_t)(HWP / 4) * c + g] = ch[c];
}

extern "C" void kernel_launch(void* const* d_in, const int* in_sizes, int n_in,
                              void* d_out, int out_size, void* d_ws, size_t ws_size,
                              hipStream_t stream) {
  const float* pred = (const float*)d_in[0];
  float* out = (float*)d_out;

  int* parent = (int*)d_ws;   // 8 * 589824 * 4 B = 18.9 MB (packed class|label)
  unsigned long long* best =
      (unsigned long long*)((char*)d_ws + (size_t)BB * HWP * sizeof(int));
  // Count scratch: channel 1 of each batch in d_out (zeroed by k_init).
  // blockmax: channel 2 region of batch 0: 24*2304*8 B = 442 KB < 2.36 MB,
  // disjoint from counts; both fully overwritten by k_final afterwards.
  unsigned long long* blockmax = (unsigned long long*)(out + (size_t)2 * HWP);

  dim3 blk(TPB);
  k_init          <<<dim3(NSLAB, BB),   blk, 0, stream>>>(pred, parent, out);
  k_bridge        <<<dim3(NBLK_BR, BB), blk, 0, stream>>>(parent);
  k_flatten_count <<<dim3(NBLK, BB),    blk, 0, stream>>>(parent, out, blockmax);
  k_reduce_best   <<<dim3(NMASK),       blk, 0, stream>>>(blockmax, best);
  k_final         <<<dim3(NBLK4, BB),   blk, 0, stream>>>(parent, best, out);
}

// Round 9
// 221.047 us; speedup vs baseline: 3.8253x; 1.0140x over previous
//
#include <hip/hip_runtime.h>
#include <stdint.h>

// Connected-components post-processor, MI355X (gfx950).
// B=8, C=4, H=W=768. argmax -> 3 disjoint class masks per batch, 4-connected
// CCL per mask, keep largest component (tie -> smallest min-raster seed),
// bg = 1 - sum(fg).
//
// Packed parent per batch: parent[b][pix] = (class<<20) | label (bg = -1).
// R8: run-scan init -- horizontal runs labeled via register ballot/scan (no
// LDS atomics for horizontal edges); vertical unions dedup'd to one per
// overlapping run pair (R8 profile: k_init 46us dominated by serial per-pixel
// LDS union chases; 2.5M bank conflicts).
//
// Pipeline:
//   k_init          argmax -> classes; run-start labels via wave scan; stitch +
//                   dedup'd vertical LDS unions; write packed parent once
//   k_bridge        cross-slab vertical edges, same-class only
//   k_flatten_count path-compress + wave-run-length count atomics; per-class
//                   (partial,~root) block max -> plain store (R3: hot atomicMax
//                   = 536us cross-XCD ping-pong -> blockmax + k_reduce_best)
//   k_reduce_best   24 blocks: max-reduce block maxima -> best[m]
//   k_final         fg = (packed parent == (cls,best_root)); 8 px/thread

constexpr int BB    = 8;
constexpr int CC    = 4;
constexpr int HH    = 768;
constexpr int WW    = 768;
constexpr int HWP   = HH * WW;          // 589824 < 2^20
constexpr int NMASK = BB * (CC - 1);    // 24
constexpr int TPB   = 256;
constexpr int NBLK  = HWP / TPB;        // 2304 (no tail)
constexpr int NBLK8 = HWP / (8 * TPB);  // 288

constexpr int SLAB_ROWS = 4;
constexpr int SLAB_PIX  = SLAB_ROWS * WW;          // 3072
constexpr int NSLAB     = HH / SLAB_ROWS;          // 192
constexpr int GR_SLAB   = SLAB_PIX / 4;            // 768 int4-groups per slab
constexpr int NBOUND    = (NSLAB - 1) * WW;        // 146688 edges per batch
constexpr int NBLK_BR   = (NBOUND + TPB - 1) / TPB;// 573 (exact)

constexpr int CSH  = 20;                 // global packed: class<<20 | pix
constexpr int LMSK = (1 << CSH) - 1;
constexpr int LSH  = 12;                 // local packed: class<<12 | lpix (<3072)
constexpr int LLMSK = (1 << LSH) - 1;

__device__ __forceinline__ int findroot(const int* __restrict__ P, int x) {
  int l = P[x] & LMSK;
  while (l != x) { x = l; l = P[x] & LMSK; }   // labels only decrease: terminates
  return x;
}

// Same-class link-to-min union-find with retry (global, packed values).
__device__ __forceinline__ void unite(int* P, int a, int b, int cls) {
  a = findroot(P, a);
  b = findroot(P, b);
  while (a != b) {
    if (a < b) { int t = a; a = b; b = t; }     // a > b: link a under b
    int old = atomicMin(&P[a], (cls << CSH) | b);
    if ((old & LMSK) == a) return;              // a was root: linked
    a = findroot(P, old & LMSK);
    b = findroot(P, b);
  }
}

// 1) argmax -> classes; zero count scratch; run-start horizontal labeling via
//    wave scan (segments of 256 px, rows = 3 aligned segments); cross-segment
//    stitch unions + dedup'd vertical unions in LDS; packed parent written
//    once with slab-rooted labels.
__global__ void __launch_bounds__(TPB)
k_init(const float* __restrict__ pred, int* __restrict__ parent,
       float* __restrict__ out) {
  __shared__ int lp[SLAB_PIX];              // 12 KB packed local union-find
  int s = blockIdx.x;                       // slab (rows [4s, 4s+4))
  int b = blockIdx.y;
  int t = threadIdx.x;
  int lane = t & 63;
  const float4* base = (const float4*)(pred + (size_t)b * CC * HWP);
  int4* cntz = (int4*)(out + (size_t)(b * CC + 1) * HWP);   // count scratch
  int4 z4 = make_int4(0, 0, 0, 0);

  unsigned char am[3][4];                   // argmax class (0..3) per pixel
#pragma unroll
  for (int i = 0; i < 3; ++i) {             // 768 groups, 256 threads
    int g = s * GR_SLAB + i * TPB + t;
    float4 v0 = base[g];
    float4 v1 = base[(size_t)(HWP / 4) + g];
    float4 v2 = base[(size_t)(HWP / 4) * 2 + g];
    float4 v3 = base[(size_t)(HWP / 4) * 3 + g];
    float c0[4] = {v0.x, v0.y, v0.z, v0.w};
    float c1[4] = {v1.x, v1.y, v1.z, v1.w};
    float c2[4] = {v2.x, v2.y, v2.z, v2.w};
    float c3[4] = {v3.x, v3.y, v3.z, v3.w};
#pragma unroll
    for (int j = 0; j < 4; ++j) {
      float bv = c0[j]; int a = 0;          // strict > keeps FIRST max (jnp.argmax)
      if (c1[j] > bv) { bv = c1[j]; a = 1; }
      if (c2[j] > bv) { bv = c2[j]; a = 2; }
      if (c3[j] > bv) { bv = c3[j]; a = 3; }
      am[i][j] = (unsigned char)a;
    }
    cntz[g] = z4;                           // zero counts for this batch

    // --- run-start scan within the 256-px wave segment ---
    int cls0 = am[i][0], cls1 = am[i][1], cls2 = am[i][2], cls3 = am[i][3];
    int c4pk = cls0 | (cls1 << 2) | (cls2 << 4) | (cls3 << 6);
    int prevl = __shfl_up(c4pk, 1) >> 6;    // prev lane's last class (lane>0)
    bool b0 = (lane == 0) || (cls0 != (prevl & 3));
    bool b1 = cls1 != cls0;
    bool b2 = cls2 != cls1;
    bool b3 = cls3 != cls2;
    int lb = b3 ? 3 : (b2 ? 2 : (b1 ? 1 : (b0 ? 0 : -1)));   // last boundary in lane
    int v = (lb >= 0) ? lane * 4 + lb : -1;
#pragma unroll
    for (int off = 1; off < 64; off <<= 1) {                 // inclusive max scan
      int o = __shfl_up(v, off);
      if (lane >= off && o > v) v = o;
    }
    int ex = __shfl_up(v, 1);               // exclusive (lane 0: unused, b0 true)
    int rs0 = b0 ? lane * 4     : ex;
    int rs1 = b1 ? lane * 4 + 1 : rs0;
    int rs2 = b2 ? lane * 4 + 2 : rs1;
    int rs3 = b3 ? lane * 4 + 3 : rs2;
    int seg = i * 1024 + (t >> 6) * 256;    // segment base (slab-local px)
    int l0  = seg + lane * 4;
    int4 iv;
    iv.x = cls0 ? (cls0 << LSH) | (seg + rs0) : -1;
    iv.y = cls1 ? (cls1 << LSH) | (seg + rs1) : -1;
    iv.z = cls2 ? (cls2 << LSH) | (seg + rs2) : -1;
    iv.w = cls3 ? (cls3 << LSH) | (seg + rs3) : -1;
    *(int4*)&lp[l0] = iv;
  }

  auto lfind = [&](int x) {
    int l = lp[x] & LLMSK;
    while (l != x) { x = l; l = lp[x] & LLMSK; }
    return x;
  };
  auto lunite = [&](int a, int c, int cls) {
    a = lfind(a); c = lfind(c);
    while (a != c) {
      if (a < c) { int tmp = a; a = c; c = tmp; }
      int old = atomicMin(&lp[a], (cls << LSH) | c);
      if ((old & LLMSK) == a) return;
      a = lfind(old & LLMSK);
      c = lfind(c);
    }
  };

  __syncthreads();

  // stitch horizontal runs across segment boundaries (lane 0, col != 0)
  if (lane == 0) {
#pragma unroll
    for (int i = 0; i < 3; ++i) {
      int seg = i * 1024 + (t >> 6) * 256;
      int cls = am[i][0];
      if (cls && (seg % WW) != 0) {
        int nv = lp[seg - 1];
        if (nv >= 0 && (nv >> LSH) == cls) lunite(seg, seg - 1, cls);
      }
    }
  }
  // vertical edges, dedup'd to one union per overlapping same-class run pair:
  // skip when the left column has the same class pair (that thread unions).
#pragma unroll
  for (int i = 0; i < 3; ++i) {
    int l0   = (i * TPB + t) * 4;
    int row  = l0 / WW;                     // 0..3 (groups never straddle rows)
    int col0 = l0 - row * WW;
    if (row == SLAB_ROWS - 1) continue;
#pragma unroll
    for (int j = 0; j < 4; ++j) {
      int cls = am[i][j];
      if (!cls) continue;
      int l = l0 + j;
      int nv = lp[l + WW];
      if (nv < 0 || (nv >> LSH) != cls) continue;
      if (col0 + j > 0) {
        int lv = lp[l - 1];
        if (lv >= 0 && (lv >> LSH) == cls) {
          int bv = lp[l + WW - 1];
          if (bv >= 0 && (bv >> LSH) == cls) continue;   // left pair unions
        }
      }
      lunite(l, l + WW, cls);
    }
  }
  __syncthreads();
  // flatten + write packed global parent (slab-rooted), coalesced int4
  int gbase = s * SLAB_PIX;
  int* Pb = parent + (size_t)b * HWP;
#pragma unroll
  for (int i = 0; i < 3; ++i) {
    int l0 = (i * TPB + t) * 4;
    int4 pv;
    pv.x = (lp[l0]     >= 0) ? ((lp[l0]     >> LSH) << CSH) | (gbase + lfind(l0))     : -1;
    pv.y = (lp[l0 + 1] >= 0) ? ((lp[l0 + 1] >> LSH) << CSH) | (gbase + lfind(l0 + 1)) : -1;
    pv.z = (lp[l0 + 2] >= 0) ? ((lp[l0 + 2] >> LSH) << CSH) | (gbase + lfind(l0 + 2)) : -1;
    pv.w = (lp[l0 + 3] >= 0) ? ((lp[l0 + 3] >> LSH) << CSH) | (gbase + lfind(l0 + 3)) : -1;
    ((int4*)Pb)[s * GR_SLAB + i * TPB + t] = pv;
  }
}

// 2) cross-slab vertical edges: rows (4k+3, 4k+4), same class only.
__global__ void __launch_bounds__(TPB)
k_bridge(int* __restrict__ parent) {
  int bp = blockIdx.x * TPB + threadIdx.x;
  if (bp >= NBOUND) return;
  int* P = parent + (size_t)blockIdx.y * HWP;
  int k = bp / WW;
  int x = bp - k * WW;
  int p = (SLAB_ROWS * k + SLAB_ROWS - 1) * WW + x;
  int pv = P[p], qv = P[p + WW];
  if (pv >= 0 && qv >= 0 && ((pv ^ qv) >> CSH) == 0)
    unite(P, p, p + WW, pv >> CSH);
}

// 3) flatten + count, fused.  Wave-aggregated size atomics (one per run of
//    equal roots); atomicAdd's return gives the running partial ->
//    pack(partial, ~root); per-class block max plain-stored to blockmax.
__global__ void __launch_bounds__(TPB)
k_flatten_count(int* __restrict__ parent, float* __restrict__ out,
                unsigned long long* __restrict__ blockmax) {
  int pix = blockIdx.x * TPB + threadIdx.x;
  int b   = blockIdx.y;
  int* P  = parent + (size_t)b * HWP;
  int pv  = P[pix];
  int r = -1, cls = 0;
  if (pv >= 0) {
    cls = pv >> CSH;
    int lbl = pv & LMSK;
    r = (lbl == pix) ? pix : findroot(P, lbl);
    if (r != lbl) P[pix] = (cls << CSH) | r;
  }
  int lane = threadIdx.x & 63;
  int prev = __shfl_up(r, 1);
  bool bound = (lane == 0) || (prev != r);
  unsigned long long lb = __ballot(bound);
  unsigned long long pack = 0ull;
  if (bound && r >= 0) {
    unsigned long long rest = (lane == 63) ? 0ull : (lb >> (lane + 1));
    int nxt = rest ? (lane + 1 + (int)__builtin_ctzll(rest)) : 64;
    int len = nxt - lane;
    uint32_t* cnt = (uint32_t*)(out + (size_t)(b * CC + 1) * HWP);
    uint32_t old = atomicAdd(cnt + r, (uint32_t)len);
    pack = (((unsigned long long)(old + (uint32_t)len)) << 32) |
           (unsigned long long)(0xFFFFFFFFu - (uint32_t)r);
  }
  __shared__ unsigned long long sm[3][TPB / 64];
  int wid = threadIdx.x >> 6;
#pragma unroll
  for (int cm = 0; cm < 3; ++cm) {
    unsigned long long pc = (cls == cm + 1) ? pack : 0ull;
#pragma unroll
    for (int off = 32; off > 0; off >>= 1) {
      unsigned long long o = __shfl_down(pc, off);
      if (o > pc) pc = o;
    }
    if (lane == 0) sm[cm][wid] = pc;
  }
  __syncthreads();
  if (threadIdx.x < 3) {
    int cm = threadIdx.x;
    unsigned long long bm = sm[cm][0];
#pragma unroll
    for (int i = 1; i < TPB / 64; ++i) if (sm[cm][i] > bm) bm = sm[cm][i];
    blockmax[(size_t)(b * 3 + cm) * NBLK + blockIdx.x] = bm;  // plain store
  }
}

// 4) reduce 2304 block maxima per (batch,class) -> best[m].  24 blocks.
__global__ void __launch_bounds__(TPB)
k_reduce_best(const unsigned long long* __restrict__ blockmax,
              unsigned long long* __restrict__ best) {
  int m = blockIdx.x;
  const unsigned long long* bm = blockmax + (size_t)m * NBLK;
  unsigned long long v = 0ull;
  for (int i = threadIdx.x; i < NBLK; i += TPB) {
    unsigned long long o = bm[i];
    if (o > v) v = o;
  }
#pragma unroll
  for (int off = 32; off > 0; off >>= 1) {
    unsigned long long o = __shfl_down(v, off);
    if (o > v) v = o;
  }
  __shared__ unsigned long long sm[TPB / 64];
  int lane = threadIdx.x & 63, wid = threadIdx.x >> 6;
  if (lane == 0) sm[wid] = v;
  __syncthreads();
  if (threadIdx.x == 0) {
    unsigned long long b0 = sm[0];
#pragma unroll
    for (int i = 1; i < TPB / 64; ++i) if (sm[i] > b0) b0 = sm[i];
    best[m] = b0;                       // 0 when mask empty
  }
}

// 5) write all 4 output channels (8 pixels/thread for more MLP).
__global__ void __launch_bounds__(TPB)
k_final(const int* __restrict__ parent, const unsigned long long* __restrict__ best,
        float* __restrict__ out) {
  int b = blockIdx.y;
  int broot[3];
#pragma unroll
  for (int cm = 0; cm < 3; ++cm) {
    unsigned long long bv = best[b * 3 + cm];            // uniform -> scalar
    broot[cm] = (bv >> 32) ? (int)(0xFFFFFFFFu - (uint32_t)bv) : -2;  // -2: empty
  }
  const int4* Pb = (const int4*)(parent + (size_t)b * HWP);
  float4* ob = (float4*)(out + (size_t)b * CC * HWP);
#pragma unroll
  for (int h = 0; h < 2; ++h) {
    int g = blockIdx.x * (2 * TPB) + h * TPB + threadIdx.x;
    int4 pv = Pb[g];
    int pvs[4] = {pv.x, pv.y, pv.z, pv.w};
    float4 ch[4];
    float* chf = (float*)ch;
#pragma unroll
    for (int c = 0; c < 4; ++c) ch[c] = make_float4(0.f, 0.f, 0.f, 0.f);
#pragma unroll
    for (int j = 0; j < 4; ++j) {
      int v = pvs[j];
      if (v >= 0) {
        int cls = v >> CSH;                  // 1..3
        bool match = (v & LMSK) == broot[cls - 1];
        chf[cls * 4 + j] = match ? 1.f : 0.f;
        chf[j]           = match ? 0.f : 1.f;   // bg
      } else {
        chf[j] = 1.f;                        // bg pixel
      }
    }
#pragma unroll
    for (int c = 0; c < 4; ++c)
      ob[(size_t)(HWP / 4) * c + g] = ch[c];
  }
}

extern "C" void kernel_launch(void* const* d_in, const int* in_sizes, int n_in,
                              void* d_out, int out_size, void* d_ws, size_t ws_size,
                              hipStream_t stream) {
  const float* pred = (const float*)d_in[0];
  float* out = (float*)d_out;

  int* parent = (int*)d_ws;   // 8 * 589824 * 4 B = 18.9 MB (packed class|label)
  unsigned long long* best =
      (unsigned long long*)((char*)d_ws + (size_t)BB * HWP * sizeof(int));
  // Count scratch: channel 1 of each batch in d_out (zeroed by k_init).
  // blockmax: channel 2 region of batch 0: 24*2304*8 B = 442 KB < 2.36 MB,
  // disjoint from counts; both fully overwritten by k_final afterwards.
  unsigned long long* blockmax = (unsigned long long*)(out + (size_t)2 * HWP);

  dim3 blk(TPB);
  k_init          <<<dim3(NSLAB, BB),   blk, 0, stream>>>(pred, parent, out);
  k_bridge        <<<dim3(NBLK_BR, BB), blk, 0, stream>>>(parent);
  k_flatten_count <<<dim3(NBLK, BB),    blk, 0, stream>>>(parent, out, blockmax);
  k_reduce_best   <<<dim3(NMASK),       blk, 0, stream>>>(blockmax, best);
  k_final         <<<dim3(NBLK8, BB),   blk, 0, stream>>>(parent, best, out);
}